// Round 6
// baseline (212.120 us; speedup 1.0000x reference)
//
#include <hip/hip_runtime.h>
#include <hip/hip_bf16.h>

typedef float v2f __attribute__((ext_vector_type(2)));

// ---------------- problem constants ----------------
#define B_    4
#define C_    4
#define Q_    8
#define J_    5
#define T_    15
#define NSIG  65536
#define N2SIG 32768
#define NOUT  16384
#define NCH   (B_ * C_)

// ---------------- wavelet filters (constexpr -> inline literals) ----------
constexpr float H0Oc[13] = {
    -0.00455690456024f, -0.00543947593727f,  0.01702522388155f,  0.02382538479492f,
    -0.10671180468666f,  0.01186609203379f,  0.56881042071212f,  0.75614564389252f,
     0.27529538466888f, -0.11720388769911f, -0.03887280126882f,  0.03466034684485f,
    -0.00388321199915f };
constexpr float H1Oc[13] = {
    -0.00388321199915f, -0.03466034684485f, -0.03887280126882f,  0.11720388769911f,
     0.27529538466888f, -0.75614564389252f,  0.56881042071212f, -0.01186609203379f,
    -0.10671180468666f, -0.02382538479492f,  0.01702522388155f,  0.00543947593727f,
    -0.00455690456024f };
constexpr float H0Ac[10] = {
     0.03516384f, 0.0f, -0.08832942f, 0.23389032f, 0.76027237f,
     0.58751830f, 0.0f, -0.11430184f, 0.0f, 0.0f };
constexpr float H0Bc[10] = {
     0.0f, 0.0f, -0.11430184f, 0.0f, 0.58751830f,
     0.76027237f, 0.23389032f, -0.08832942f, 0.0f, 0.03516384f };
constexpr float H1Ac[10] = {
     0.0f, 0.0f, -0.11430184f, 0.0f, 0.58751830f,
    -0.76027237f, 0.23389032f, 0.08832942f, 0.0f, -0.03516384f };
constexpr float H1Bc[10] = {
    -0.03516384f, 0.0f, 0.08832942f, 0.23389032f, -0.76027237f,
     0.58751830f, 0.0f, -0.11430184f, 0.0f, 0.0f };

// fused two-stage lowpass+decimate: out[m] = sum_n g[n] * u[4m + n - 18]
struct Gtab { float v[37]; };
constexpr Gtab make_g() {
    Gtab g{};
    for (int n = 0; n < 37; ++n) {
        float s = 0.f;
        for (int k = 0; k < 13; ++k) {
            int l = n - 2 * k;
            if (l >= 0 && l < 13) s += H0Oc[k] * H0Oc[l];
        }
        g.v[n] = s;
    }
    return g;
}
constexpr Gtab cG = make_g();

// ---------------- tiling (M2=64, merged chain, 8 blocks/CU) ---------------
// Round-5 lesson: merged chain (9 convs vs 15) is right but at M2=128 the
// 27KB LDS gave ~3 resident blocks + a 1.33-round tail -> VALUBusy 54%.
// M2=64 shrinks LDS to 16.8KB -> 8 blocks/CU (= 2048-thread HW cap) and
// grid 4096 = EXACTLY 2 residency rounds (no partial tail). Chain halo
// overhead +~6us vs M2=128 is the price; overlap should more than repay.
#define M2    64                 // final outputs per tile
#define MTN   (NOUT / M2)        // 256 tiles
#define MTLAST (MTN - 1)
#define NUcnt 289                // 4*(M2-1) + 37
#define NUP   296                // padded U plane stride (v2f elems)
#define NBcnt 401                // NUcnt + 112 (D=8 tap halo)
#define NBP   408
#define S_    552                // x window: [0, 547) needed, padded

// LDS carve (floats):
//   X  @ [0,552)   | L1 @ [552,1104)
//   PP0 = v2f @ float 0     (p in [19,528) -> floats [38,1056); X,L1 dead at lv2)
//   PP1 = v2f @ float 1104  (p in [10,537) -> floats [1124,2178) c [1104,2208))
//   U0  = v2f @ float 2208  | U1 = v2f @ float 2800   (592 floats each)
//   sRI = v2f @ float 3392  -> end 4208 floats = 16832 B; x8 = 134.7KB OK
#define SMEM_FLOATS (4 * S_ + 4 * NUP + 2 * NBP)   // 4208

__device__ __forceinline__ v2f zmask(v2f a, bool ok) {
    if (!ok) { a.x = 0.f; a.y = 0.f; }
    return a;
}

// ---------------- post stage (u + fused downsample), templated on D ------
// NOTE (r1): U planes stay INTERLEAVED (linear writes, up[4*mo+n] reads);
// the 16-way read conflict is hidden under VALU issue — fixing it regressed.
// NOTE (r3): keep launch-bound VGPR cap >= ~84 or taps[15] spills (666MB).
template<int D>
__device__ __forceinline__ void post_stage(
        const v2f* __restrict__ sRI, v2f* __restrict__ U0, v2f* __restrict__ U1,
        const float* __restrict__ cw, const float* __restrict__ roots,
        float beta, int j, int b, int c, int m0, int mt, int tid,
        float* __restrict__ out) {
    const float lg_is = -0.5f * (float)j;                // log2(inv_scale)
    const float beta2 = beta * exp2f(0.5f * (float)j);   // beta * scale
    const int   u_lo  = 4 * m0 - 18;
    // ds split: tid<128 active, qp = tid>>6 (wave-uniform), mo = tid&63
    const int   qp  = (tid >> 6) & 1;
    const int   mo  = tid & 63;
    const int   m   = m0 + mo;
    const bool edge = (mt == 0 && mo < 3) || (mt == MTLAST && mo >= 61);

    for (int g2 = 0; g2 < 2; ++g2) {
        // uniform weights / alphas for this group of 4 q's (wave-uniform
        // addresses -> s_loads, live in SGPRs)
        float w[4][T_], al[4], cq[4];
        #pragma unroll
        for (int qq = 0; qq < 4; ++qq) {
            const int o = c * Q_ + g2 * 4 + qq;
            #pragma unroll
            for (int t = 0; t < T_; t++) w[qq][t] = cw[(size_t)(j * 32 + o) * T_ + t];
            al[qq] = 1.f / (1.f + __expf(-roots[j * 32 + o]));
            cq[qq] = al[qq] * lg_is;
        }

        // ---- u stage: batched tap reads (r2-proven form) ----
        for (int i = tid; i < NUcnt; i += 256) {
            const int n = u_lo + i;
            const bool ok = ((unsigned)n < (unsigned)NSIG);
            const v2f* tp = sRI + (i + 56 - 7 * D);
            v2f taps[T_];
            #pragma unroll
            for (int t = 0; t < T_; t++) taps[t] = tp[t * D];
            float uq[4];
            #pragma unroll
            for (int qq = 0; qq < 4; ++qq) {
                v2f ri; ri.x = 0.f; ri.y = 0.f;
                #pragma unroll
                for (int t = 0; t < T_; t++) ri += w[qq][t] * taps[t];
                float z2 = fmaf(ri.x, ri.x, ri.y * ri.y);
                // single-instruction transcendentals (v_sqrt/v_log/v_exp)
                float us = __builtin_amdgcn_sqrtf(z2);
                float lg = __builtin_amdgcn_logf(us + beta2);
                float u  = __builtin_amdgcn_exp2f(fmaf(al[qq], lg, cq[qq]));
                uq[qq] = ok ? u : 0.f;
            }
            v2f p0; p0.x = uq[0]; p0.y = uq[1];
            v2f p1; p1.x = uq[2]; p1.y = uq[3];
            U0[i] = p0; U1[i] = p1;
        }
        __syncthreads();

        // ---- fused 37-tap stride-4 downsample (threads 0..127) ----
        if (tid < 128) {
            const v2f* up = qp ? U1 : U0;
            const v2f* ub = up + 4 * mo;
            v2f acc; acc.x = 0.f; acc.y = 0.f;
            #pragma unroll
            for (int n = 0; n < 37; ++n) acc += cG.v[n] * ub[n];
            if (edge) {
                // exact two-stage computation honoring v-plane masking
                v2f a2; a2.x = 0.f; a2.y = 0.f;
                for (int k = 0; k < 13; ++k) {
                    int p = 2 * m + k - 6;
                    if (p < 0 || p >= N2SIG) continue;
                    v2f v; v.x = 0.f; v.y = 0.f;
                    for (int l = 0; l < 13; ++l)
                        v += H0Oc[l] * up[4 * mo + 2 * k + l];
                    a2 += H0Oc[k] * v;
                }
                acc = a2;
            }
            const int o = c * Q_ + g2 * 4 + 2 * qp;
            out[((size_t)b * 160 + j * 32 + o)     * NOUT + m] = acc.x;
            out[((size_t)b * 160 + j * 32 + o + 1) * NOUT + m] = acc.y;
        }
        __syncthreads();   // protect U planes before next group's writes
    }
}

// ---------------- fused kernel: one block = one tile, ALL 5 j's ----------
// launch_bounds (256,6): VGPR cap ~84 — no forced spill (r3 lesson);
// natural VGPR ~40 <= 64 lets HW reach 8 blocks/CU anyway.
__global__ __launch_bounds__(256, 6) void murenn_all(
        const float* __restrict__ x,
        const float* __restrict__ cw,
        const float* __restrict__ roots,
        const float* __restrict__ beta_p,
        float* __restrict__ out) {
    __shared__ __align__(16) float smem[SMEM_FLOATS];
    float* X   = smem;                        // [0,552)
    float* L1  = smem + S_;                   // [552,1104)
    v2f*   PP0 = (v2f*)smem;                  // aliases X/L1 (both dead at lv2)
    v2f*   PP1 = (v2f*)(smem + 2 * S_);       // floats [1104,2208)
    v2f*   U0  = (v2f*)(smem + 4 * S_);       // floats [2208,2800) DEDICATED
    v2f*   U1  = (v2f*)(smem + 4 * S_ + 2 * NUP);  // floats [2800,3392)
    v2f*   sRI = (v2f*)(smem + 4 * S_ + 4 * NUP);  // floats [3392,4208)

    const int tid = threadIdx.x;
    const int mt  = blockIdx.x;               // 0..255
    const int ch  = blockIdx.y;               // b*C + c
    const int b   = ch >> 2, c = ch & 3;
    const int m0  = mt * M2;
    const int ofs = 4 * m0 - 147;             // window start (bp index 0 at p=73)
    const float beta = beta_p[0];
    const float* xc = x + (size_t)ch * NSIG;

    // ---- load x window (ONCE per tile, serves all 5 j's) ----
    for (int p = tid; p < S_; p += 256) {
        int g = ofs + p;
        X[p] = ((unsigned)g < (unsigned)NSIG) ? xc[g] : 0.f;
    }
    __syncthreads();

    // ================= level 0 =================
    // band0: conv13(X, H1O) -> sRI   (reads X[67,480) c [0,552))
    for (int i = tid; i < NBcnt; i += 256) {
        int p = 73 + i, g = ofs + p;
        float a = 0.f;
        #pragma unroll
        for (int k = 0; k < 13; k++) a += H1Oc[k] * X[p + k - 6];
        if ((unsigned)g >= (unsigned)NSIG) a = 0.f;
        v2f r; r.x = a; r.y = a;
        sRI[i] = r;
    }
    __syncthreads();
    post_stage<1>(sRI, U0, U1, cw, roots, beta, 0, b, c, m0, mt, tid, out);

    // lv0: conv13(X, H0O) -> L1 on [6,541)  (reads X[0,547))
    for (int p = 6 + tid; p < 541; p += 256) {
        int g = ofs + p;
        float a = 0.f;
        #pragma unroll
        for (int k = 0; k < 13; k++) a += H0Oc[k] * X[p + k - 6];
        L1[p] = ((unsigned)g < (unsigned)NSIG) ? a : 0.f;
    }
    __syncthreads();

    // ================= level 1 =================
    // band1: conv10(L1, H1A/H1B) -> sRI   (reads L1[69,470) c [6,541))
    for (int i = tid; i < NBcnt; i += 256) {
        int p = 73 + i, g = ofs + p;
        v2f r; r.x = 0.f; r.y = 0.f;
        #pragma unroll
        for (int k = 0; k < 10; k++) {
            v2f hk; hk.x = H1Ac[k]; hk.y = H1Bc[k];
            r += hk * L1[p + k - 4];
        }
        sRI[i] = zmask(r, (unsigned)g < (unsigned)NSIG);
    }
    __syncthreads();
    post_stage<1>(sRI, U0, U1, cw, roots, beta, 1, b, c, m0, mt, tid, out);

    // lv1 (d=1, pad 4): (la2,lb2) -> PP1 on [10,537)  (reads L1[6,541))
    for (int p = 10 + tid; p < 537; p += 256) {
        int g = ofs + p;
        v2f a; a.x = 0.f; a.y = 0.f;
        #pragma unroll
        for (int k = 0; k < 10; k++) {
            v2f hk; hk.x = H0Ac[k]; hk.y = H0Bc[k];
            a += hk * L1[p + k - 4];
        }
        PP1[p] = zmask(a, (unsigned)g < (unsigned)NSIG);
    }
    __syncthreads();

    // ================= level 2 =================
    // band2: (PP1, 2k-9) -> sRI   (reads PP1[64,465) c [10,537))
    for (int i = tid; i < NBcnt; i += 256) {
        int p = 73 + i, g = ofs + p;
        v2f r; r.x = 0.f; r.y = 0.f;
        #pragma unroll
        for (int k = 0; k < 10; k++) {
            v2f hk; hk.x = H1Ac[k]; hk.y = H1Bc[k];
            r += hk * PP1[p + 2 * k - 9];
        }
        sRI[i] = zmask(r, (unsigned)g < (unsigned)NSIG);
    }
    __syncthreads();
    post_stage<2>(sRI, U0, U1, cw, roots, beta, 2, b, c, m0, mt, tid, out);

    // lv2 (d=2, pad 9): (la3,lb3) -> PP0 on [19,528)  (reads PP1[10,537))
    // PP0 floats [38,1056): X and L1 both dead here (lv1/band1 done)
    for (int p = 19 + tid; p < 528; p += 256) {
        int g = ofs + p;
        v2f a; a.x = 0.f; a.y = 0.f;
        #pragma unroll
        for (int k = 0; k < 10; k++) {
            v2f hk; hk.x = H0Ac[k]; hk.y = H0Bc[k];
            a += hk * PP1[p + 2 * k - 9];
        }
        PP0[p] = zmask(a, (unsigned)g < (unsigned)NSIG);
    }
    __syncthreads();

    // ================= level 3 =================
    // band3: (PP0, 4k-18) -> sRI   (reads PP0[55,492) c [19,528))
    for (int i = tid; i < NBcnt; i += 256) {
        int p = 73 + i, g = ofs + p;
        v2f r; r.x = 0.f; r.y = 0.f;
        #pragma unroll
        for (int k = 0; k < 10; k++) {
            v2f hk; hk.x = H1Ac[k]; hk.y = H1Bc[k];
            r += hk * PP0[p + 4 * k - 18];
        }
        sRI[i] = zmask(r, (unsigned)g < (unsigned)NSIG);
    }
    __syncthreads();
    post_stage<4>(sRI, U0, U1, cw, roots, beta, 3, b, c, m0, mt, tid, out);

    // lv3 (d=4, pad 18): (la4,lb4) -> PP1 on [37,510)  (reads PP0[19,528))
    for (int p = 37 + tid; p < 510; p += 256) {
        int g = ofs + p;
        v2f a; a.x = 0.f; a.y = 0.f;
        #pragma unroll
        for (int k = 0; k < 10; k++) {
            v2f hk; hk.x = H0Ac[k]; hk.y = H0Bc[k];
            a += hk * PP0[p + 4 * k - 18];
        }
        PP1[p] = zmask(a, (unsigned)g < (unsigned)NSIG);
    }
    __syncthreads();

    // ================= level 4 =================
    // band4: (PP1, 8k-36) -> sRI   (reads PP1[37,510) exactly)
    for (int i = tid; i < NBcnt; i += 256) {
        int p = 73 + i, g = ofs + p;
        v2f r; r.x = 0.f; r.y = 0.f;
        #pragma unroll
        for (int k = 0; k < 10; k++) {
            v2f hk; hk.x = H1Ac[k]; hk.y = H1Bc[k];
            r += hk * PP1[p + 8 * k - 36];
        }
        sRI[i] = zmask(r, (unsigned)g < (unsigned)NSIG);
    }
    __syncthreads();
    post_stage<8>(sRI, U0, U1, cw, roots, beta, 4, b, c, m0, mt, tid, out);
}

// ---------------- launch ----------------
extern "C" void kernel_launch(void* const* d_in, const int* in_sizes, int n_in,
                              void* d_out, int out_size, void* d_ws, size_t ws_size,
                              hipStream_t stream) {
    (void)in_sizes; (void)n_in; (void)out_size; (void)d_ws; (void)ws_size;
    const float* x     = (const float*)d_in[0];
    const float* cw    = (const float*)d_in[1];
    const float* roots = (const float*)d_in[2];
    const float* beta  = (const float*)d_in[3];
    float* out = (float*)d_out;

    dim3 grid(MTN, NCH);                 // (256, 16) = 4096 uniform blocks
    murenn_all<<<grid, 256, 0, stream>>>(x, cw, roots, beta, out);
}

// Round 7
// 180.763 us; speedup vs baseline: 1.1735x; 1.1735x over previous
//
#include <hip/hip_runtime.h>
#include <hip/hip_bf16.h>

typedef float v2f __attribute__((ext_vector_type(2)));

// ---------------- problem constants ----------------
#define B_    4
#define C_    4
#define Q_    8
#define J_    5
#define T_    15
#define NSIG  65536
#define N2SIG 32768
#define NOUT  16384
#define NCH   (B_ * C_)

// ---------------- wavelet filters (constexpr -> inline literals) ----------
constexpr float H0Oc[13] = {
    -0.00455690456024f, -0.00543947593727f,  0.01702522388155f,  0.02382538479492f,
    -0.10671180468666f,  0.01186609203379f,  0.56881042071212f,  0.75614564389252f,
     0.27529538466888f, -0.11720388769911f, -0.03887280126882f,  0.03466034684485f,
    -0.00388321199915f };
constexpr float H1Oc[13] = {
    -0.00388321199915f, -0.03466034684485f, -0.03887280126882f,  0.11720388769911f,
     0.27529538466888f, -0.75614564389252f,  0.56881042071212f, -0.01186609203379f,
    -0.10671180468666f, -0.02382538479492f,  0.01702522388155f,  0.00543947593727f,
    -0.00455690456024f };
constexpr float H0Ac[10] = {
     0.03516384f, 0.0f, -0.08832942f, 0.23389032f, 0.76027237f,
     0.58751830f, 0.0f, -0.11430184f, 0.0f, 0.0f };
constexpr float H0Bc[10] = {
     0.0f, 0.0f, -0.11430184f, 0.0f, 0.58751830f,
     0.76027237f, 0.23389032f, -0.08832942f, 0.0f, 0.03516384f };
constexpr float H1Ac[10] = {
     0.0f, 0.0f, -0.11430184f, 0.0f, 0.58751830f,
    -0.76027237f, 0.23389032f, 0.08832942f, 0.0f, -0.03516384f };
constexpr float H1Bc[10] = {
    -0.03516384f, 0.0f, 0.08832942f, 0.23389032f, -0.76027237f,
     0.58751830f, 0.0f, -0.11430184f, 0.0f, 0.0f };

// fused two-stage lowpass+decimate: out[m] = sum_n g[n] * u[4m + n - 18]
// g[n] = sum_k h[k] * h[n-2k], support 37 taps
struct Gtab { float v[37]; };
constexpr Gtab make_g() {
    Gtab g{};
    for (int n = 0; n < 37; ++n) {
        float s = 0.f;
        for (int k = 0; k < 13; ++k) {
            int l = n - 2 * k;
            if (l >= 0 && l < 13) s += H0Oc[k] * H0Oc[l];
        }
        g.v[n] = s;
    }
    return g;
}
constexpr Gtab cG = make_g();

// ---------------- tiling (EXACT r2 structure: per-j grid, M2=256) ---------
// Round-5/6 lesson: merged-chain kernels lose to barrier convoy regardless
// of tile size. r2 (per-j, M2=256, 114us) is the proven structure; this
// round only changes the U-plane LAYOUT (see below).
#define M2    256                // final outputs per tile
#define NUcnt 1057               // 4*(M2-1) + 37
#define NBcnt 1169               // bp pairs needed
#define NBP   1176
#define S_    1320               // x window (halo 73 left / 74 right)

// U-plane layout: u[i] stored at index i + (i>>2)  (stride-5/4 padding).
// - ds read of out m: taps at up[5*m + (n + (n>>2))] -> ONE base address +
//   37 compile-time immediate offsets (preserves the batched-read pattern
//   whose loss sank r1), banks (5*lane mod 16) cover all 16 bank-pairs ->
//   4 lanes/bank-pair = b64 conflict-free minimum (was 16-way, ~64% of
//   all LDS cycles per the r6 ledger).
// - write at i+(i>>2): injective, near-linear, ~1.25x (free per m136).
#define UPLANE 1328              // v2f per U plane: max idx 1056+264=1320, pad
__device__ __forceinline__ int uidx(int i) { return i + (i >> 2); }

// LDS carve (floats): [0,1320) X | [1320,2640) L1 | PP0=v2f@0 | PP1=v2f@2640
// U0=v2f@0 (1328 v2f) | U1=v2f@2656 (1328 v2f, aliases dead PP region)
// sRI=v2f@5312 (1176 v2f) -> total 7664 floats = 30656B (same 30720 granule)
#define SMEM_FLOATS (4 * UPLANE + 2 * NBP)   // 7664

__device__ __forceinline__ v2f zmask(v2f a, bool ok) {
    if (!ok) { a.x = 0.f; a.y = 0.f; }
    return a;
}

// ---------------- post stage (u + fused downsample), templated on D ------
template<int D>
__device__ __forceinline__ void post_stage(
        const v2f* __restrict__ sRI, v2f* __restrict__ U0, v2f* __restrict__ U1,
        const float* __restrict__ cw, const float* __restrict__ roots,
        float beta, int j, int b, int c, int m0, int mt, int tid,
        float* __restrict__ out) {
    const float lg_is = -0.5f * (float)j;                // log2(inv_scale)
    const float beta2 = beta * exp2f(0.5f * (float)j);   // beta * scale
    const int   u_lo  = 4 * m0 - 18;

    for (int g2 = 0; g2 < 2; ++g2) {
        // uniform weights / alphas for this group of 4 q's (wave-uniform
        // addresses -> s_loads, live in SGPRs)
        float w[4][T_], al[4], cq[4];
        #pragma unroll
        for (int qq = 0; qq < 4; ++qq) {
            const int o = c * Q_ + g2 * 4 + qq;
            #pragma unroll
            for (int t = 0; t < T_; t++) w[qq][t] = cw[(size_t)(j * 32 + o) * T_ + t];
            al[qq] = 1.f / (1.f + __expf(-roots[j * 32 + o]));
            cq[qq] = al[qq] * lg_is;
        }

        // ---- u stage: batched tap reads (r2-proven form, UNCHANGED) ----
        for (int i = tid; i < NUcnt; i += 256) {
            const int n = u_lo + i;
            const bool ok = ((unsigned)n < (unsigned)NSIG);
            const v2f* tp = sRI + (i + 56 - 7 * D);
            v2f taps[T_];
            #pragma unroll
            for (int t = 0; t < T_; t++) taps[t] = tp[t * D];
            float uq[4];
            #pragma unroll
            for (int qq = 0; qq < 4; ++qq) {
                v2f ri; ri.x = 0.f; ri.y = 0.f;
                #pragma unroll
                for (int t = 0; t < T_; t++) ri += w[qq][t] * taps[t];
                float z2 = fmaf(ri.x, ri.x, ri.y * ri.y);
                // single-instruction transcendentals (v_sqrt/v_log/v_exp)
                float us = __builtin_amdgcn_sqrtf(z2);
                float lg = __builtin_amdgcn_logf(us + beta2);
                float u  = __builtin_amdgcn_exp2f(fmaf(al[qq], lg, cq[qq]));
                uq[qq] = ok ? u : 0.f;
            }
            v2f p0; p0.x = uq[0]; p0.y = uq[1];
            v2f p1; p1.x = uq[2]; p1.y = uq[3];
            const int wi = uidx(i);          // strided-5/4 store
            U0[wi] = p0; U1[wi] = p1;
        }
        __syncthreads();

        // ---- fused 37-tap stride-4 downsample, conflict-free layout ----
        {
            const int m = m0 + tid;                 // tid < 256 always
            const bool edge = (mt == 0 && tid < 3) || (mt == 63 && tid >= 253);
            #pragma unroll
            for (int qp = 0; qp < 2; ++qp) {
                const v2f* up = qp ? U1 : U0;
                const v2f* ub = up + 5 * tid;       // uidx(4*tid) = 5*tid
                v2f acc; acc.x = 0.f; acc.y = 0.f;
                #pragma unroll
                for (int n = 0; n < 37; ++n)
                    acc += cG.v[n] * ub[n + (n >> 2)];   // imm offsets
                if (edge) {
                    // exact two-stage computation honoring v-plane masking
                    v2f a2; a2.x = 0.f; a2.y = 0.f;
                    for (int k = 0; k < 13; ++k) {
                        int p = 2 * m + k - 6;
                        if (p < 0 || p >= N2SIG) continue;
                        v2f v; v.x = 0.f; v.y = 0.f;
                        for (int l = 0; l < 13; ++l)
                            v += H0Oc[l] * up[uidx(4 * tid + 2 * k + l)];
                        a2 += H0Oc[k] * v;
                    }
                    acc = a2;
                }
                const int o = c * Q_ + g2 * 4 + 2 * qp;
                out[((size_t)b * 160 + j * 32 + o)     * NOUT + m] = acc.x;
                out[((size_t)b * 160 + j * 32 + o + 1) * NOUT + m] = acc.y;
            }
        }
        __syncthreads();   // protect U planes before next group's writes
    }
}

// ---------------- fused kernel (EXACT r2 structure) ----------------------
__global__ __launch_bounds__(256, 5) void murenn_all(
        const float* __restrict__ x,
        const float* __restrict__ cw,
        const float* __restrict__ roots,
        const float* __restrict__ beta_p,
        float* __restrict__ out) {
    __shared__ __align__(16) float smem[SMEM_FLOATS];
    float* X   = smem;                       // [0,1320)
    float* L1  = smem + S_;                  // [1320,2640)
    v2f*   PP0 = (v2f*)smem;                 // aliases X/L1 (used after dead)
    v2f*   PP1 = (v2f*)(smem + 2 * S_);      // floats [2640,5280)
    v2f*   U0  = (v2f*)smem;                 // aliases chain region (dead then)
    v2f*   U1  = (v2f*)(smem + 2 * UPLANE);  // floats [2656,5312)
    v2f*   sRI = (v2f*)(smem + 4 * UPLANE);  // floats [5312,7664)

    const int tid = threadIdx.x;
    // j varies FASTEST in dispatch order: mixes the 5x work-imbalanced j
    // cohorts across CUs (kills the long-j tail).
    const int j   = blockIdx.x;              // 0..4
    const int mt  = blockIdx.y;              // 0..63
    const int ch  = blockIdx.z;              // b*C + c
    const int b   = ch >> 2, c = ch & 3;
    const int m0  = mt * M2;
    const int ofs = 4 * m0 - 147;            // window start (bp index 0 at p=73)
    const float beta = beta_p[0];
    const float* xc = x + (size_t)ch * NSIG;

    // ---- load x window ----
    for (int p = tid; p < S_; p += 256) {
        int g = ofs + p;
        X[p] = ((unsigned)g < (unsigned)NSIG) ? xc[g] : 0.f;
    }
    __syncthreads();

    // ---- UDTCWT chain (branches block-uniform in j) ----
    if (j == 0) {
        for (int i = tid; i < NBcnt; i += 256) {
            int p = 73 + i, g = ofs + p;
            float a = 0.f;
            #pragma unroll
            for (int k = 0; k < 13; k++) a += H1Oc[k] * X[p + k - 6];
            if ((unsigned)g >= (unsigned)NSIG) a = 0.f;
            v2f r; r.x = a; r.y = a;
            sRI[i] = r;
        }
    } else {
        // lv0: la1 = conv13(x, H0O) -> L1
        for (int p = 6 + tid; p < 1313; p += 256) {
            int g = ofs + p;
            float a = 0.f;
            #pragma unroll
            for (int k = 0; k < 13; k++) a += H0Oc[k] * X[p + k - 6];
            L1[p] = ((unsigned)g < (unsigned)NSIG) ? a : 0.f;
        }
        __syncthreads();
        if (j == 1) {
            for (int i = tid; i < NBcnt; i += 256) {
                int p = 73 + i, g = ofs + p;
                v2f r; r.x = 0.f; r.y = 0.f;
                #pragma unroll
                for (int k = 0; k < 10; k++) {
                    v2f hk; hk.x = H1Ac[k]; hk.y = H1Bc[k];
                    r += hk * L1[p + k - 4];
                }
                sRI[i] = zmask(r, (unsigned)g < (unsigned)NSIG);
            }
        } else {
            // lv1 (d=1, pad 4): (la2,lb2) -> PP1
            for (int p = 10 + tid; p < 1308; p += 256) {
                int g = ofs + p;
                v2f a; a.x = 0.f; a.y = 0.f;
                #pragma unroll
                for (int k = 0; k < 10; k++) {
                    v2f hk; hk.x = H0Ac[k]; hk.y = H0Bc[k];
                    a += hk * L1[p + k - 4];
                }
                PP1[p] = zmask(a, (unsigned)g < (unsigned)NSIG);
            }
            __syncthreads();
            if (j == 2) {
                for (int i = tid; i < NBcnt; i += 256) {
                    int p = 73 + i, g = ofs + p;
                    v2f r; r.x = 0.f; r.y = 0.f;
                    #pragma unroll
                    for (int k = 0; k < 10; k++) {
                        v2f hk; hk.x = H1Ac[k]; hk.y = H1Bc[k];
                        r += hk * PP1[p + 2 * k - 9];
                    }
                    sRI[i] = zmask(r, (unsigned)g < (unsigned)NSIG);
                }
            } else {
                // lv2 (d=2, pad 9): (la3,lb3) -> PP0  (X/L1 dead)
                for (int p = 19 + tid; p < 1299; p += 256) {
                    int g = ofs + p;
                    v2f a; a.x = 0.f; a.y = 0.f;
                    #pragma unroll
                    for (int k = 0; k < 10; k++) {
                        v2f hk; hk.x = H0Ac[k]; hk.y = H0Bc[k];
                        a += hk * PP1[p + 2 * k - 9];
                    }
                    PP0[p] = zmask(a, (unsigned)g < (unsigned)NSIG);
                }
                __syncthreads();
                if (j == 3) {
                    for (int i = tid; i < NBcnt; i += 256) {
                        int p = 73 + i, g = ofs + p;
                        v2f r; r.x = 0.f; r.y = 0.f;
                        #pragma unroll
                        for (int k = 0; k < 10; k++) {
                            v2f hk; hk.x = H1Ac[k]; hk.y = H1Bc[k];
                            r += hk * PP0[p + 4 * k - 18];
                        }
                        sRI[i] = zmask(r, (unsigned)g < (unsigned)NSIG);
                    }
                } else {
                    // lv3 (d=4, pad 18): (la4,lb4) -> PP1 (old PP1 dead)
                    for (int p = 37 + tid; p < 1281; p += 256) {
                        int g = ofs + p;
                        v2f a; a.x = 0.f; a.y = 0.f;
                        #pragma unroll
                        for (int k = 0; k < 10; k++) {
                            v2f hk; hk.x = H0Ac[k]; hk.y = H0Bc[k];
                            a += hk * PP0[p + 4 * k - 18];
                        }
                        PP1[p] = zmask(a, (unsigned)g < (unsigned)NSIG);
                    }
                    __syncthreads();
                    // j == 4 bandpass (d=8, pad 36)
                    for (int i = tid; i < NBcnt; i += 256) {
                        int p = 73 + i, g = ofs + p;
                        v2f r; r.x = 0.f; r.y = 0.f;
                        #pragma unroll
                        for (int k = 0; k < 10; k++) {
                            v2f hk; hk.x = H1Ac[k]; hk.y = H1Bc[k];
                            r += hk * PP1[p + 8 * k - 36];
                        }
                        sRI[i] = zmask(r, (unsigned)g < (unsigned)NSIG);
                    }
                }
            }
        }
    }
    __syncthreads();
    // PP/X/L1 dead: region becomes U planes.

    if (j == 0)      post_stage<1>(sRI, U0, U1, cw, roots, beta, 0, b, c, m0, mt, tid, out);
    else if (j == 1) post_stage<1>(sRI, U0, U1, cw, roots, beta, 1, b, c, m0, mt, tid, out);
    else if (j == 2) post_stage<2>(sRI, U0, U1, cw, roots, beta, 2, b, c, m0, mt, tid, out);
    else if (j == 3) post_stage<4>(sRI, U0, U1, cw, roots, beta, 3, b, c, m0, mt, tid, out);
    else             post_stage<8>(sRI, U0, U1, cw, roots, beta, 4, b, c, m0, mt, tid, out);
}

// ---------------- launch ----------------
extern "C" void kernel_launch(void* const* d_in, const int* in_sizes, int n_in,
                              void* d_out, int out_size, void* d_ws, size_t ws_size,
                              hipStream_t stream) {
    (void)in_sizes; (void)n_in; (void)out_size; (void)d_ws; (void)ws_size;
    const float* x     = (const float*)d_in[0];
    const float* cw    = (const float*)d_in[1];
    const float* roots = (const float*)d_in[2];
    const float* beta  = (const float*)d_in[3];
    float* out = (float*)d_out;

    dim3 grid(J_, NOUT / M2, NCH);       // (5, 64, 16), j fastest
    murenn_all<<<grid, 256, 0, stream>>>(x, cw, roots, beta, out);
}

// Round 8
// 162.302 us; speedup vs baseline: 1.3069x; 1.1137x over previous
//
#include <hip/hip_runtime.h>
#include <hip/hip_bf16.h>

typedef float v2f __attribute__((ext_vector_type(2)));

// ---------------- problem constants ----------------
#define B_    4
#define C_    4
#define Q_    8
#define J_    5
#define T_    15
#define NSIG  65536
#define N2SIG 32768
#define NOUT  16384
#define NCH   (B_ * C_)

// ---------------- wavelet filters (constexpr -> inline literals) ----------
constexpr float H0Oc[13] = {
    -0.00455690456024f, -0.00543947593727f,  0.01702522388155f,  0.02382538479492f,
    -0.10671180468666f,  0.01186609203379f,  0.56881042071212f,  0.75614564389252f,
     0.27529538466888f, -0.11720388769911f, -0.03887280126882f,  0.03466034684485f,
    -0.00388321199915f };
constexpr float H1Oc[13] = {
    -0.00388321199915f, -0.03466034684485f, -0.03887280126882f,  0.11720388769911f,
     0.27529538466888f, -0.75614564389252f,  0.56881042071212f, -0.01186609203379f,
    -0.10671180468666f, -0.02382538479492f,  0.01702522388155f,  0.00543947593727f,
    -0.00455690456024f };
constexpr float H0Ac[10] = {
     0.03516384f, 0.0f, -0.08832942f, 0.23389032f, 0.76027237f,
     0.58751830f, 0.0f, -0.11430184f, 0.0f, 0.0f };
constexpr float H0Bc[10] = {
     0.0f, 0.0f, -0.11430184f, 0.0f, 0.58751830f,
     0.76027237f, 0.23389032f, -0.08832942f, 0.0f, 0.03516384f };
constexpr float H1Ac[10] = {
     0.0f, 0.0f, -0.11430184f, 0.0f, 0.58751830f,
    -0.76027237f, 0.23389032f, 0.08832942f, 0.0f, -0.03516384f };
constexpr float H1Bc[10] = {
    -0.03516384f, 0.0f, 0.08832942f, 0.23389032f, -0.76027237f,
     0.58751830f, 0.0f, -0.11430184f, 0.0f, 0.0f };

// fused two-stage lowpass+decimate: out[m] = sum_n g[n] * u[4m + n - 18]
struct Gtab { float v[37]; };
constexpr Gtab make_g() {
    Gtab g{};
    for (int n = 0; n < 37; ++n) {
        float s = 0.f;
        for (int k = 0; k < 13; ++k) {
            int l = n - 2 * k;
            if (l >= 0 && l < 13) s += H0Oc[k] * H0Oc[l];
        }
        g.v[n] = s;
    }
    return g;
}
constexpr Gtab cG = make_g();

// ---------------- tiling (EXACT r2 structure: per-j grid, M2=256) ---------
// History: r2 = 114us champion. r1/r7: conflict-free U layouts BOTH
// regressed (conflicts are fully hidden; contiguity wins) — U stays
// interleaved. r3: forced occupancy -> spill disaster. r5/r6: merged
// chain -> barrier convoy. This round: EDGE templating only (interior
// tiles skip all bounds masks — block-uniform condition) + mt-fastest
// grid (r0's FETCH was 3.1MB vs j-fastest 12.6MB).
#define M2    256                // final outputs per tile
#define NUcnt 1057               // 4*(M2-1) + 37
#define NUP   1064               // padded U plane stride (v2f elems)
#define NBcnt 1169               // bp pairs needed
#define NBP   1176
#define S_    1320               // x window (halo 73 left / 74 right)

// LDS carve (floats): [0,1320) X | [1320,2640) L1 | PP0=v2f@0 (1320) |
// PP1=v2f@2640 (1320) | U0=v2f@0 (1064) | U1=v2f@2128 (1064) | sRI=v2f@5280
#define SMEM_FLOATS (5280 + 2 * NBP)   // 7632 floats = 30528 B

__device__ __forceinline__ v2f zmask(v2f a, bool ok) {
    if (!ok) { a.x = 0.f; a.y = 0.f; }
    return a;
}

// ---------------- post stage (u + fused downsample) ----------------------
// U planes deliberately INTERLEAVED (r1/r7 lessons — do not "fix").
template<int D, bool EDGE>
__device__ __forceinline__ void post_stage(
        const v2f* __restrict__ sRI, v2f* __restrict__ U0, v2f* __restrict__ U1,
        const float* __restrict__ cw, const float* __restrict__ roots,
        float beta, int j, int b, int c, int m0, int mt, int tid,
        float* __restrict__ out) {
    const float lg_is = -0.5f * (float)j;                // log2(inv_scale)
    const float beta2 = beta * exp2f(0.5f * (float)j);   // beta * scale
    const int   u_lo  = 4 * m0 - 18;

    for (int g2 = 0; g2 < 2; ++g2) {
        // uniform weights / alphas (wave-uniform addresses -> SGPRs)
        float w[4][T_], al[4], cq[4];
        #pragma unroll
        for (int qq = 0; qq < 4; ++qq) {
            const int o = c * Q_ + g2 * 4 + qq;
            #pragma unroll
            for (int t = 0; t < T_; t++) w[qq][t] = cw[(size_t)(j * 32 + o) * T_ + t];
            al[qq] = 1.f / (1.f + __expf(-roots[j * 32 + o]));
            cq[qq] = al[qq] * lg_is;
        }

        // ---- u stage: batched tap reads (r2-proven form) ----
        for (int i = tid; i < NUcnt; i += 256) {
            const v2f* tp = sRI + (i + 56 - 7 * D);
            v2f taps[T_];
            #pragma unroll
            for (int t = 0; t < T_; t++) taps[t] = tp[t * D];
            bool ok = true;
            if constexpr (EDGE) {
                const int n = u_lo + i;
                ok = ((unsigned)n < (unsigned)NSIG);
            }
            float uq[4];
            #pragma unroll
            for (int qq = 0; qq < 4; ++qq) {
                v2f ri; ri.x = 0.f; ri.y = 0.f;
                #pragma unroll
                for (int t = 0; t < T_; t++) ri += w[qq][t] * taps[t];
                float z2 = fmaf(ri.x, ri.x, ri.y * ri.y);
                // single-instruction transcendentals (v_sqrt/v_log/v_exp)
                float us = __builtin_amdgcn_sqrtf(z2);
                float lg = __builtin_amdgcn_logf(us + beta2);
                float u  = __builtin_amdgcn_exp2f(fmaf(al[qq], lg, cq[qq]));
                if constexpr (EDGE) uq[qq] = ok ? u : 0.f;
                else                uq[qq] = u;
            }
            v2f p0; p0.x = uq[0]; p0.y = uq[1];
            v2f p1; p1.x = uq[2]; p1.y = uq[3];
            U0[i] = p0; U1[i] = p1;
        }
        __syncthreads();

        // ---- fused 37-tap stride-4 downsample, q-pair packed ----
        {
            const int m = m0 + tid;                 // tid < 256 always
            #pragma unroll
            for (int qp = 0; qp < 2; ++qp) {
                const v2f* up = qp ? U1 : U0;
                const v2f* ub = up + 4 * tid;
                v2f acc; acc.x = 0.f; acc.y = 0.f;
                #pragma unroll
                for (int n = 0; n < 37; ++n) acc += cG.v[n] * ub[n];
                if constexpr (EDGE) {
                    const bool edge = (mt == 0 && tid < 3) || (mt == 63 && tid >= 253);
                    if (edge) {
                        // exact two-stage computation honoring v-plane masking
                        v2f a2; a2.x = 0.f; a2.y = 0.f;
                        for (int k = 0; k < 13; ++k) {
                            int p = 2 * m + k - 6;
                            if (p < 0 || p >= N2SIG) continue;
                            v2f v; v.x = 0.f; v.y = 0.f;
                            for (int l = 0; l < 13; ++l)
                                v += H0Oc[l] * up[4 * tid + 2 * k + l];
                            a2 += H0Oc[k] * v;
                        }
                        acc = a2;
                    }
                }
                const int o = c * Q_ + g2 * 4 + 2 * qp;
                out[((size_t)b * 160 + j * 32 + o)     * NOUT + m] = acc.x;
                out[((size_t)b * 160 + j * 32 + o + 1) * NOUT + m] = acc.y;
            }
        }
        __syncthreads();   // protect U planes before next group's writes
    }
}

// ---------------- whole tile, templated on block-uniform EDGE ------------
template<bool EDGE>
__device__ __forceinline__ void run_tile(
        float* __restrict__ smem,
        const float* __restrict__ x, const float* __restrict__ cw,
        const float* __restrict__ roots, float beta,
        float* __restrict__ out, int j, int mt, int ch, int tid) {
    float* X   = smem;                       // [0,1320)
    float* L1  = smem + S_;                  // [1320,2640)
    v2f*   PP0 = (v2f*)smem;                 // aliases X/L1 (used after dead)
    v2f*   PP1 = (v2f*)(smem + 2 * S_);      // floats [2640,5280)
    v2f*   U0  = (v2f*)smem;                 // aliases PP region (dead then)
    v2f*   U1  = (v2f*)(smem + 2 * NUP);
    v2f*   sRI = (v2f*)(smem + 4 * S_);      // floats [5280,7632)

    const int b   = ch >> 2, c = ch & 3;
    const int m0  = mt * M2;
    const int ofs = 4 * m0 - 147;            // window start (bp index 0 at p=73)
    const float* xc = x + (size_t)ch * NSIG;

    // ---- load x window ----
    for (int p = tid; p < S_; p += 256) {
        if constexpr (EDGE) {
            int g = ofs + p;
            X[p] = ((unsigned)g < (unsigned)NSIG) ? xc[g] : 0.f;
        } else {
            X[p] = xc[ofs + p];
        }
    }
    __syncthreads();

    // ---- UDTCWT chain (branches block-uniform in j) ----
    if (j == 0) {
        for (int i = tid; i < NBcnt; i += 256) {
            int p = 73 + i;
            float a = 0.f;
            #pragma unroll
            for (int k = 0; k < 13; k++) a += H1Oc[k] * X[p + k - 6];
            if constexpr (EDGE) { if ((unsigned)(ofs + p) >= (unsigned)NSIG) a = 0.f; }
            v2f r; r.x = a; r.y = a;
            sRI[i] = r;
        }
    } else {
        // lv0: la1 = conv13(x, H0O) -> L1
        for (int p = 6 + tid; p < 1313; p += 256) {
            float a = 0.f;
            #pragma unroll
            for (int k = 0; k < 13; k++) a += H0Oc[k] * X[p + k - 6];
            if constexpr (EDGE) { if ((unsigned)(ofs + p) >= (unsigned)NSIG) a = 0.f; }
            L1[p] = a;
        }
        __syncthreads();
        if (j == 1) {
            for (int i = tid; i < NBcnt; i += 256) {
                int p = 73 + i;
                v2f r; r.x = 0.f; r.y = 0.f;
                #pragma unroll
                for (int k = 0; k < 10; k++) {
                    v2f hk; hk.x = H1Ac[k]; hk.y = H1Bc[k];
                    r += hk * L1[p + k - 4];
                }
                if constexpr (EDGE) r = zmask(r, (unsigned)(ofs + p) < (unsigned)NSIG);
                sRI[i] = r;
            }
        } else {
            // lv1 (d=1, pad 4): (la2,lb2) -> PP1
            for (int p = 10 + tid; p < 1308; p += 256) {
                v2f a; a.x = 0.f; a.y = 0.f;
                #pragma unroll
                for (int k = 0; k < 10; k++) {
                    v2f hk; hk.x = H0Ac[k]; hk.y = H0Bc[k];
                    a += hk * L1[p + k - 4];
                }
                if constexpr (EDGE) a = zmask(a, (unsigned)(ofs + p) < (unsigned)NSIG);
                PP1[p] = a;
            }
            __syncthreads();
            if (j == 2) {
                for (int i = tid; i < NBcnt; i += 256) {
                    int p = 73 + i;
                    v2f r; r.x = 0.f; r.y = 0.f;
                    #pragma unroll
                    for (int k = 0; k < 10; k++) {
                        v2f hk; hk.x = H1Ac[k]; hk.y = H1Bc[k];
                        r += hk * PP1[p + 2 * k - 9];
                    }
                    if constexpr (EDGE) r = zmask(r, (unsigned)(ofs + p) < (unsigned)NSIG);
                    sRI[i] = r;
                }
            } else {
                // lv2 (d=2, pad 9): (la3,lb3) -> PP0  (X/L1 dead)
                for (int p = 19 + tid; p < 1299; p += 256) {
                    v2f a; a.x = 0.f; a.y = 0.f;
                    #pragma unroll
                    for (int k = 0; k < 10; k++) {
                        v2f hk; hk.x = H0Ac[k]; hk.y = H0Bc[k];
                        a += hk * PP1[p + 2 * k - 9];
                    }
                    if constexpr (EDGE) a = zmask(a, (unsigned)(ofs + p) < (unsigned)NSIG);
                    PP0[p] = a;
                }
                __syncthreads();
                if (j == 3) {
                    for (int i = tid; i < NBcnt; i += 256) {
                        int p = 73 + i;
                        v2f r; r.x = 0.f; r.y = 0.f;
                        #pragma unroll
                        for (int k = 0; k < 10; k++) {
                            v2f hk; hk.x = H1Ac[k]; hk.y = H1Bc[k];
                            r += hk * PP0[p + 4 * k - 18];
                        }
                        if constexpr (EDGE) r = zmask(r, (unsigned)(ofs + p) < (unsigned)NSIG);
                        sRI[i] = r;
                    }
                } else {
                    // lv3 (d=4, pad 18): (la4,lb4) -> PP1 (old PP1 dead)
                    for (int p = 37 + tid; p < 1281; p += 256) {
                        v2f a; a.x = 0.f; a.y = 0.f;
                        #pragma unroll
                        for (int k = 0; k < 10; k++) {
                            v2f hk; hk.x = H0Ac[k]; hk.y = H0Bc[k];
                            a += hk * PP0[p + 4 * k - 18];
                        }
                        if constexpr (EDGE) a = zmask(a, (unsigned)(ofs + p) < (unsigned)NSIG);
                        PP1[p] = a;
                    }
                    __syncthreads();
                    // j == 4 bandpass (d=8, pad 36)
                    for (int i = tid; i < NBcnt; i += 256) {
                        int p = 73 + i;
                        v2f r; r.x = 0.f; r.y = 0.f;
                        #pragma unroll
                        for (int k = 0; k < 10; k++) {
                            v2f hk; hk.x = H1Ac[k]; hk.y = H1Bc[k];
                            r += hk * PP1[p + 8 * k - 36];
                        }
                        if constexpr (EDGE) r = zmask(r, (unsigned)(ofs + p) < (unsigned)NSIG);
                        sRI[i] = r;
                    }
                }
            }
        }
    }
    __syncthreads();
    // PP/X/L1 dead: region becomes U planes.

    float beta_ = beta;
    if (j == 0)      post_stage<1, EDGE>(sRI, U0, U1, cw, roots, beta_, 0, b, c, m0, mt, tid, out);
    else if (j == 1) post_stage<1, EDGE>(sRI, U0, U1, cw, roots, beta_, 1, b, c, m0, mt, tid, out);
    else if (j == 2) post_stage<2, EDGE>(sRI, U0, U1, cw, roots, beta_, 2, b, c, m0, mt, tid, out);
    else if (j == 3) post_stage<4, EDGE>(sRI, U0, U1, cw, roots, beta_, 3, b, c, m0, mt, tid, out);
    else             post_stage<8, EDGE>(sRI, U0, U1, cw, roots, beta_, 4, b, c, m0, mt, tid, out);
}

// ---------------- fused kernel ----------------
__global__ __launch_bounds__(256, 5) void murenn_all(
        const float* __restrict__ x,
        const float* __restrict__ cw,
        const float* __restrict__ roots,
        const float* __restrict__ beta_p,
        float* __restrict__ out) {
    __shared__ __align__(16) float smem[SMEM_FLOATS];
    const int tid = threadIdx.x;
    const int mt  = blockIdx.x;              // 0..63 (fastest: L3 x-locality)
    const int ch  = blockIdx.y;              // b*C + c
    const int j   = blockIdx.z;              // 0..4
    const float beta = beta_p[0];

    // Interior tiles (mt 1..62): window [4*m0-147, +1320) and u-range
    // [4*m0-18, 4*m0+1039) provably inside [0,NSIG) -> all bounds masks
    // compile out. Edge tiles (2/64) take the fully-masked path.
    if (mt == 0 || mt == 63)
        run_tile<true >(smem, x, cw, roots, beta, out, j, mt, ch, tid);
    else
        run_tile<false>(smem, x, cw, roots, beta, out, j, mt, ch, tid);
}

// ---------------- launch ----------------
extern "C" void kernel_launch(void* const* d_in, const int* in_sizes, int n_in,
                              void* d_out, int out_size, void* d_ws, size_t ws_size,
                              hipStream_t stream) {
    (void)in_sizes; (void)n_in; (void)out_size; (void)d_ws; (void)ws_size;
    const float* x     = (const float*)d_in[0];
    const float* cw    = (const float*)d_in[1];
    const float* roots = (const float*)d_in[2];
    const float* beta  = (const float*)d_in[3];
    float* out = (float*)d_out;

    dim3 grid(NOUT / M2, NCH, J_);       // (64, 16, 5), mt fastest
    murenn_all<<<grid, 256, 0, stream>>>(x, cw, roots, beta, out);
}